// Round 1
// baseline (1273.318 us; speedup 1.0000x reference)
//
#include <hip/hip_runtime.h>
#include <math.h>

#define B_ 2
#define N_ 1024
#define E_ 512
#define H_ 8
#define DH_ 64
#define KMAX_ 8
#define M_NODES 2047   // total tree nodes across levels 0..10

// ---------------- wave helpers ----------------
__device__ __forceinline__ float wsum(float v) {
  v += __shfl_xor(v, 1);  v += __shfl_xor(v, 2);  v += __shfl_xor(v, 4);
  v += __shfl_xor(v, 8);  v += __shfl_xor(v, 16); v += __shfl_xor(v, 32);
  return v;
}
__device__ __forceinline__ float wmaxr(float v) {
  v = fmaxf(v, __shfl_xor(v, 1));  v = fmaxf(v, __shfl_xor(v, 2));
  v = fmaxf(v, __shfl_xor(v, 4));  v = fmaxf(v, __shfl_xor(v, 8));
  v = fmaxf(v, __shfl_xor(v, 16)); v = fmaxf(v, __shfl_xor(v, 32));
  return v;
}
__device__ __forceinline__ float sigmoidf_(float x) { return 1.f / (1.f + __expf(-x)); }

// ---------------- W2 = (ddqW[p] + I) * sc_d[p], p<10 ----------------
__global__ void build_w2(const float* __restrict__ ddqW, const float* __restrict__ ddqT,
                         float* __restrict__ W2) {
  int idx = blockIdx.x * 256 + threadIdx.x;
  if (idx >= 10 * 64 * 64) return;
  int p = idx >> 12;
  int r = (idx >> 6) & 63;
  int d = idx & 63;
  float t = ddqT[p];
  float sp = log1pf(__expf(t));
  float scd = 1.f / ((sp + 1e-6f) * 8.0f);   // 1/((softplus+1e-6)*sqrt(DH))
  W2[idx] = (ddqW[idx] + (r == d ? 1.f : 0.f)) * scd;
}

// ---------------- tiled fp32 GEMM, C[m][n] = sum_k A[m][k]*Brow[n][k] ----------------
// MODE 0: fused projections (N=2560, B rows from 5 weight mats; routing epilogue)
// MODE 1: Qall (A=q as 16384x64, B=W2 as 640x64; write scaled depth-queries)
// MODE 2: final out-proj (bias b0, plain store)
template<int MODE>
__global__ __launch_bounds__(256, 2)
void gemm_tn(const float* __restrict__ A, int M, int N, int K,
             const float* __restrict__ w0, const float* __restrict__ w1,
             const float* __restrict__ w2m, const float* __restrict__ w3,
             const float* __restrict__ w4,
             const float* __restrict__ b0, const float* __restrict__ b1,
             const float* __restrict__ b2, const float* __restrict__ b3,
             const float* __restrict__ b4,
             float* __restrict__ qbuf, float* __restrict__ bank,
             float* __restrict__ klbuf, float* __restrict__ vlbuf,
             float* __restrict__ gatebuf, float* __restrict__ qsout,
             float* __restrict__ oout)
{
  __shared__ float As[16][136];
  __shared__ float Bs[16][136];
  const int tid = threadIdx.x;
  const int tx = tid & 15, ty = tid >> 4;
  const int row0 = blockIdx.y * 128;
  const int col0 = blockIdx.x * 128;
  float acc[8][8];
#pragma unroll
  for (int i = 0; i < 8; ++i)
#pragma unroll
    for (int j = 0; j < 8; ++j) acc[i][j] = 0.f;

  const int lr = tid >> 1;          // 0..127
  const int lc = (tid & 1) * 8;     // 0 or 8
  const float* arow = A + (size_t)(row0 + lr) * K + lc;
  const int bcol = col0 + lr;
  const float* brow;
  if (MODE == 0) {
    int sel = bcol >> 9;
    const float* w = sel == 0 ? w0 : sel == 1 ? w1 : sel == 2 ? w2m : sel == 3 ? w3 : w4;
    brow = w + (size_t)(bcol & 511) * K + lc;
  } else {
    brow = w0 + (size_t)bcol * K + lc;
  }

  for (int kt = 0; kt < K; kt += 16) {
    float4 a0  = *(const float4*)(arow + kt);
    float4 a1  = *(const float4*)(arow + kt + 4);
    float4 bb0 = *(const float4*)(brow + kt);
    float4 bb1 = *(const float4*)(brow + kt + 4);
    __syncthreads();
    As[lc + 0][lr] = a0.x;  As[lc + 1][lr] = a0.y;  As[lc + 2][lr] = a0.z;  As[lc + 3][lr] = a0.w;
    As[lc + 4][lr] = a1.x;  As[lc + 5][lr] = a1.y;  As[lc + 6][lr] = a1.z;  As[lc + 7][lr] = a1.w;
    Bs[lc + 0][lr] = bb0.x; Bs[lc + 1][lr] = bb0.y; Bs[lc + 2][lr] = bb0.z; Bs[lc + 3][lr] = bb0.w;
    Bs[lc + 4][lr] = bb1.x; Bs[lc + 5][lr] = bb1.y; Bs[lc + 6][lr] = bb1.z; Bs[lc + 7][lr] = bb1.w;
    __syncthreads();
#pragma unroll
    for (int kk = 0; kk < 16; ++kk) {
      float4 af0 = *(const float4*)&As[kk][ty * 8];
      float4 af1 = *(const float4*)&As[kk][ty * 8 + 4];
      float4 bf0 = *(const float4*)&Bs[kk][tx * 8];
      float4 bf1 = *(const float4*)&Bs[kk][tx * 8 + 4];
      float av[8] = {af0.x, af0.y, af0.z, af0.w, af1.x, af1.y, af1.z, af1.w};
      float bv[8] = {bf0.x, bf0.y, bf0.z, bf0.w, bf1.x, bf1.y, bf1.z, bf1.w};
#pragma unroll
      for (int i = 0; i < 8; ++i)
#pragma unroll
        for (int j = 0; j < 8; ++j)
          acc[i][j] = fmaf(av[i], bv[j], acc[i][j]);
    }
  }

  if (MODE == 0) {
    const int sel = col0 >> 9;   // uniform per block (128 | 512)
#pragma unroll
    for (int i = 0; i < 8; ++i) {
      const int row = row0 + ty * 8 + i;
      const int bb = row >> 10;
      const int nn = row & 1023;
#pragma unroll
      for (int j = 0; j < 8; ++j) {
        const int col = col0 + tx * 8 + j;
        const int c = col & 511;
        float v = acc[i][j];
        if (sel == 0) {
          qbuf[(size_t)row * 512 + c] = v + b0[c];
        } else if (sel == 1) {
          int hh = c >> 6, dd = c & 63;   // v -> bank level 0, slot 0
          bank[((size_t)(bb * 8 + hh) * M_NODES + nn) * 512 + dd] = v + b1[c];
        } else if (sel == 2) {
          klbuf[(size_t)row * 512 + c] = v + b2[c];
        } else if (sel == 3) {
          vlbuf[(size_t)row * 512 + c] = v + b3[c];
        } else {
          gatebuf[(size_t)row * 512 + c] = sigmoidf_(v + b4[c]);
        }
      }
    }
  } else if (MODE == 1) {
#pragma unroll
    for (int i = 0; i < 8; ++i) {
      const int row = row0 + ty * 8 + i;
#pragma unroll
      for (int j = 0; j < 8; ++j) {
        const int col = col0 + tx * 8 + j;
        qsout[((size_t)(col >> 6) * 16384 + row) * 64 + (col & 63)] = acc[i][j];
      }
    }
  } else {
#pragma unroll
    for (int i = 0; i < 8; ++i) {
      const int row = row0 + ty * 8 + i;
#pragma unroll
      for (int j = 0; j < 8; ++j) {
        const int col = col0 + tx * 8 + j;
        oout[(size_t)row * 512 + col] = acc[i][j] + b0[col];
      }
    }
  }
}

// ---------------- tree level update (level D reads level D-1) ----------------
template<int D>
__global__ __launch_bounds__(512, 1)
void level_kernel(const float* __restrict__ glW, const float* __restrict__ glb,
                  const float* __restrict__ grW, const float* __restrict__ grb,
                  const float* __restrict__ pq, const float* __restrict__ lnG,
                  const float* __restrict__ lnB, const float* __restrict__ skA,
                  const float* __restrict__ skW, const float* __restrict__ coup,
                  const float* __restrict__ wfreq, const float* __restrict__ wdamp,
                  const float* __restrict__ wphase, float* __restrict__ bank)
{
  constexpr int KPREV = ((D - 1) >= 3) ? 8 : (1 << (D - 1));
  constexpr int SLOTS = 2 * KPREV;
  constexpr int KP = (D >= 3) ? 8 : (1 << D);
  const int node = blockIdx.x;
  const int b = blockIdx.y;
  const int h = threadIdx.x >> 6;
  const int lane = threadIdx.x & 63;
  __shared__ __align__(16) float wbuf[64 * 132];
  __shared__ __align__(16) float gin[8][128];
  __shared__ float parlds[8][KP][64];

  const int base_prev = 2048 - (2048 >> (D - 1));
  const int base_cur  = 2048 - (2048 >> D);
  const size_t bh = (size_t)(b * H_ + h);
  const float* bl  = bank + (bh * M_NODES + base_prev + 2 * node) * 512;
  const float* brp = bank + (bh * M_NODES + base_prev + 2 * node + 1) * 512;

  const float alpha = log1pf(__expf(wdamp[h]));
  const float dec = __expf(-alpha);
  const float ang = wfreq[h] + wphase[h] + (float)D * 0.78539816339744831f;
  const float pr  = dec * cosf(ang);
  const float pim = dec * sinf(ang);

  float fL[KPREV], rot[KPREV];
  float lm = 0.f, rm = 0.f;
#pragma unroll
  for (int k = 0; k < KPREV; ++k) {
    fL[k] = bl[k * 64 + lane];
    float fr = brp[k * 64 + lane];
    float partner = __shfl_xor(fr, 32);
    rot[k] = (lane < 32) ? (pr * fr - pim * partner) : (pim * partner + pr * fr);
    lm += fL[k]; rm += rot[k];
  }
  lm *= (1.f / KPREV); rm *= (1.f / KPREV);
  gin[h][lane] = lm;
  gin[h][64 + lane] = rm;
  __syncthreads();

  // ---- gl ----
  for (int i = threadIdx.x; i < 64 * 128; i += 512)
    wbuf[(i >> 7) * 132 + (i & 127)] = glW[D * 64 * 128 + i];
  __syncthreads();
  float gl = glb[D * 64 + lane];
  {
    const float4* gin4 = (const float4*)&gin[h][0];
#pragma unroll
    for (int e4 = 0; e4 < 32; ++e4) {
      float4 wv = *(const float4*)&wbuf[lane * 132 + e4 * 4];
      float4 gv = gin4[e4];
      gl += gv.x * wv.x + gv.y * wv.y + gv.z * wv.z + gv.w * wv.w;
    }
  }
  gl = sigmoidf_(gl);
  __syncthreads();

  // ---- gr ----
  for (int i = threadIdx.x; i < 64 * 128; i += 512)
    wbuf[(i >> 7) * 132 + (i & 127)] = grW[D * 64 * 128 + i];
  __syncthreads();
  float gr = grb[D * 64 + lane];
  {
    const float4* gin4 = (const float4*)&gin[h][0];
#pragma unroll
    for (int e4 = 0; e4 < 32; ++e4) {
      float4 wv = *(const float4*)&wbuf[lane * 132 + e4 * 4];
      float4 gv = gin4[e4];
      gr += gv.x * wv.x + gv.y * wv.y + gv.z * wv.z + gv.w * wv.w;
    }
  }
  gr = sigmoidf_(gr);
  __syncthreads();

  // ---- skip matvec: sk = lm @ skW[D].T ----
  for (int i = threadIdx.x; i < 64 * 64; i += 512)
    wbuf[(i >> 6) * 68 + (i & 63)] = skW[D * 64 * 64 + i];
  __syncthreads();
  float sk = 0.f;
  {
    const float4* gin4 = (const float4*)&gin[h][0];  // first 64 = lm
#pragma unroll
    for (int e4 = 0; e4 < 16; ++e4) {
      float4 wv = *(const float4*)&wbuf[lane * 68 + e4 * 4];
      float4 gv = gin4[e4];
      sk += gv.x * wv.x + gv.y * wv.y + gv.z * wv.z + gv.w * wv.w;
    }
  }

  float slot[SLOTS];
#pragma unroll
  for (int k = 0; k < KPREV; ++k) { slot[k] = fL[k] * gl; slot[KPREV + k] = rot[k] * gr; }

  // ---- attention pooling over slots ----
  float par[KP];
#pragma unroll
  for (int qi = 0; qi < KP; ++qi) {
    float pqv = pq[(D * KMAX_ + qi) * 64 + lane];
    float lg[SLOTS];
    float mx = -1e30f;
#pragma unroll
    for (int kk = 0; kk < SLOTS; ++kk) {
      lg[kk] = wsum(pqv * slot[kk]) * 0.125f;
      mx = fmaxf(mx, lg[kk]);
    }
    float den = 0.f, pv = 0.f;
#pragma unroll
    for (int kk = 0; kk < SLOTS; ++kk) {
      float w = __expf(lg[kk] - mx);
      den += w;
      pv += w * slot[kk];
    }
    par[qi] = pv / den;
  }

  // ---- LN + skip ----
  const float sig_sk = sigmoidf_(skA[D]);
#pragma unroll
  for (int qi = 0; qi < KP; ++qi) {
    float mu = wsum(par[qi]) * (1.f / 64.f);
    float dv = par[qi] - mu;
    float var = wsum(dv * dv) * (1.f / 64.f);
    float nv = dv * rsqrtf(var + 1e-5f);
    par[qi] = nv * lnG[D * 64 + lane] + lnB[D * 64 + lane] + sig_sk * sk;
    parlds[h][qi][lane] = par[qi];
  }
  __syncthreads();

  // ---- head coupling ----
  float cw[8];
  float cmx = -1e30f;
#pragma unroll
  for (int j = 0; j < 8; ++j) { cw[j] = coup[(D * H_ + h) * H_ + j]; cmx = fmaxf(cmx, cw[j]); }
  float cs = 0.f;
#pragma unroll
  for (int j = 0; j < 8; ++j) { cw[j] = __expf(cw[j] - cmx); cs += cw[j]; }
  const float cinv = 1.f / cs;
  const size_t obase = (bh * M_NODES + base_cur + node) * 512;
#pragma unroll
  for (int qi = 0; qi < KP; ++qi) {
    float o = 0.f;
#pragma unroll
    for (int j = 0; j < 8; ++j) o += cw[j] * parlds[j][qi][lane];
    bank[obase + qi * 64 + lane] = o * cinv;
  }
}

// ---------------- local window attn + tree attn + gate combine ----------------
__global__ __launch_bounds__(512, 1)
void combine_kernel(const float* __restrict__ qbuf, const float* __restrict__ klbuf,
                    const float* __restrict__ vlbuf, const float* __restrict__ gatebuf,
                    const float* __restrict__ bank, const float* __restrict__ Qs,
                    float* __restrict__ outpre)
{
  const int n = blockIdx.x;
  const int b = blockIdx.y;
  const int h = threadIdx.x >> 6;
  const int lane = threadIdx.x & 63;
  __shared__ int pair_ro[64];
  __shared__ int pair_sl[64];
  __shared__ int sdepth[16];
  __shared__ int PS[2];
  __shared__ __align__(16) float Qlds[8][10][68];

  if (threadIdx.x == 0) {
    int l = 2048, r = 2048 + n;
    int cnt = 0, sc = 0;
    while (l < r) {
      if (l & 1) {
        int node = l++;
        int d = 11 - (31 - __clz(node));
        int half = 2048 >> d;
        int gidx = (2048 - half) + (node - half);
        sdepth[sc] = d;
        int kv = (d >= 3) ? 8 : (1 << d);
        for (int k = 0; k < kv; ++k) { pair_ro[cnt] = (gidx * 8 + k) * 64; pair_sl[cnt] = sc; ++cnt; }
        ++sc;
      }
      if (r & 1) {
        int node = --r;
        int d = 11 - (31 - __clz(node));
        int half = 2048 >> d;
        int gidx = (2048 - half) + (node - half);
        sdepth[sc] = d;
        int kv = (d >= 3) ? 8 : (1 << d);
        for (int k = 0; k < kv; ++k) { pair_ro[cnt] = (gidx * 8 + k) * 64; pair_sl[cnt] = sc; ++cnt; }
        ++sc;
      }
      l >>= 1; r >>= 1;
    }
    PS[0] = cnt; PS[1] = sc;
  }
  __syncthreads();
  const int P = PS[0], S = PS[1];
  const size_t vbase = ((size_t)(b * N_ + n) * H_ + h) * 64;

  // stage this head's depth-queries
  for (int s = 0; s < S; ++s) {
    int d = sdepth[s];
    Qlds[h][s][lane] = Qs[((size_t)d * (B_ * N_ * H_) + (size_t)(b * N_ + n) * H_ + h) * 64 + lane];
  }
  __syncthreads();

  // ---- local sliding-window attention ----
  float qv = qbuf[vbase + lane];
  const int wmax = (n + 1 < 32) ? (n + 1) : 32;
  float myscore = -1e30f;
  for (int w = 0; w < wmax; ++w) {
    float kv = klbuf[vbase - (size_t)w * 512 + lane];
    float s = wsum(qv * kv) * 0.125f;
    if (lane == w) myscore = s;
  }
  float lmax = wmaxr(myscore);
  float le = (lane < wmax) ? __expf(myscore - lmax) : 0.f;
  float lden = wsum(le);
  float lp = le / lden;
  float local = 0.f;
  for (int w = 0; w < wmax; ++w) {
    float pw = __shfl(lp, w);
    local += pw * vlbuf[vbase - (size_t)w * 512 + lane];
  }

  // ---- tree attention (one lane per (cover-node, slot) pair) ----
  const size_t bhbase = (size_t)(b * H_ + h) * M_NODES * 512;
  float tree = 0.f;
  if (P > 0) {
    float logit = -1e30f;
    if (lane < P) {
      const float4* b4 = (const float4*)(bank + bhbase + pair_ro[lane]);
      const float4* q4 = (const float4*)&Qlds[h][pair_sl[lane]][0];
      float a = 0.f;
#pragma unroll
      for (int i = 0; i < 16; ++i) {
        float4 bb = b4[i];
        float4 qq = q4[i];
        a += qq.x * bb.x + qq.y * bb.y + qq.z * bb.z + qq.w * bb.w;
      }
      logit = a;
    }
    float tm = wmaxr(logit);
    float te = (lane < P) ? __expf(logit - tm) : 0.f;
    float tden = wsum(te);
    float tw = te / tden;
    for (int l2 = 0; l2 < P; ++l2) {
      float wl = __shfl(tw, l2);
      tree += wl * bank[bhbase + pair_ro[l2] + lane];
    }
  }

  float g = gatebuf[vbase + lane];
  outpre[vbase + lane] = local + g * tree;
}

// ---------------- launcher ----------------
extern "C" void kernel_launch(void* const* d_in, const int* in_sizes, int n_in,
                              void* d_out, int out_size, void* d_ws, size_t ws_size,
                              hipStream_t stream)
{
  (void)in_sizes; (void)n_in; (void)out_size; (void)ws_size;
  const float* x     = (const float*)d_in[0];
  const float* qW    = (const float*)d_in[1];
  const float* qb    = (const float*)d_in[2];
  const float* vW    = (const float*)d_in[3];
  const float* vb    = (const float*)d_in[4];
  const float* oW    = (const float*)d_in[5];
  const float* ob    = (const float*)d_in[6];
  const float* klW   = (const float*)d_in[7];
  const float* klb   = (const float*)d_in[8];
  const float* vlW   = (const float*)d_in[9];
  const float* vlb   = (const float*)d_in[10];
  const float* gW    = (const float*)d_in[11];
  const float* gb    = (const float*)d_in[12];
  const float* ddqW  = (const float*)d_in[13];
  const float* ddqT  = (const float*)d_in[14];
  const float* wfreq = (const float*)d_in[15];
  const float* wdamp = (const float*)d_in[16];
  const float* wphase= (const float*)d_in[17];
  const float* glW   = (const float*)d_in[18];
  const float* glb   = (const float*)d_in[19];
  const float* grW   = (const float*)d_in[20];
  const float* grb   = (const float*)d_in[21];
  const float* pq    = (const float*)d_in[22];
  const float* lnG   = (const float*)d_in[23];
  const float* lnB   = (const float*)d_in[24];
  const float* skA   = (const float*)d_in[25];
  const float* skW   = (const float*)d_in[26];
  const float* coup  = (const float*)d_in[27];
  // d_in[28..31] (cov_idx / cov_depth / cov_mask / kvalid) recomputed on device.

  float* ws = (float*)d_ws;
  float* qbuf    = ws; ws += (size_t)2048 * 512;
  float* klbuf   = ws; ws += (size_t)2048 * 512;
  float* vlbuf   = ws; ws += (size_t)2048 * 512;
  float* gatebuf = ws; ws += (size_t)2048 * 512;
  float* outpre  = ws; ws += (size_t)2048 * 512;
  float* bank    = ws; ws += (size_t)16 * M_NODES * 512;   // (B,H,M,KMAX,DH)
  float* Qs      = ws; ws += (size_t)10 * 16384 * 64;      // (depth, b*n*h, DH), pre-scaled
  float* W2      = ws; ws += (size_t)10 * 64 * 64;

  build_w2<<<160, 256, 0, stream>>>(ddqW, ddqT, W2);

  // fused projections: q | v->bank L0 | k_loc | v_loc | sigmoid-gate
  gemm_tn<0><<<dim3(20, 16), 256, 0, stream>>>(x, 2048, 2560, 512,
      qW, vW, klW, vlW, gW, qb, vb, klb, vlb, gb,
      qbuf, bank, klbuf, vlbuf, gatebuf, nullptr, nullptr);

  // depth-queries Qall_scaled = q @ W2[p].T
  gemm_tn<1><<<dim3(5, 128), 256, 0, stream>>>(qbuf, 16384, 640, 64,
      W2, nullptr, nullptr, nullptr, nullptr,
      nullptr, nullptr, nullptr, nullptr, nullptr,
      nullptr, nullptr, nullptr, nullptr, nullptr, Qs, nullptr);

#define LVL(DD) level_kernel<DD><<<dim3(1024 >> DD, 2), 512, 0, stream>>>( \
      glW, glb, grW, grb, pq, lnG, lnB, skA, skW, coup, wfreq, wdamp, wphase, bank)
  LVL(1); LVL(2); LVL(3); LVL(4); LVL(5); LVL(6); LVL(7); LVL(8); LVL(9);
#undef LVL

  combine_kernel<<<dim3(1024, 2), 512, 0, stream>>>(qbuf, klbuf, vlbuf, gatebuf, bank, Qs, outpre);

  // final projection
  gemm_tn<2><<<dim3(4, 16), 256, 0, stream>>>(outpre, 2048, 512, 512,
      oW, nullptr, nullptr, nullptr, nullptr,
      ob, nullptr, nullptr, nullptr, nullptr,
      nullptr, nullptr, nullptr, nullptr, nullptr, nullptr, (float*)d_out);
}

// Round 2
// 575.789 us; speedup vs baseline: 2.2114x; 2.2114x over previous
//
#include <hip/hip_runtime.h>
#include <math.h>

#define B_ 2
#define N_ 1024
#define H_ 8
#define TOTV 5104   // compact bank vectors per (b,h): sum_d nodes_d * ks_d

typedef __attribute__((ext_vector_type(8))) short bf16x8;
typedef __attribute__((ext_vector_type(4))) float f32x4;

__device__ __constant__ int VBASE[11] = {0,1024,2048,3072,4096,4608,4864,4992,5056,5088,5104};

constexpr int vbase_of(int d) {
  int v = 0;
  for (int i = 0; i < d; ++i) v += (1024 >> i) * ((i >= 3) ? 8 : (1 << i));
  return v;
}

// ---------------- helpers ----------------
__device__ __forceinline__ float wsum(float v) {
  v += __shfl_xor(v, 1);  v += __shfl_xor(v, 2);  v += __shfl_xor(v, 4);
  v += __shfl_xor(v, 8);  v += __shfl_xor(v, 16); v += __shfl_xor(v, 32);
  return v;
}
__device__ __forceinline__ float wmaxr(float v) {
  v = fmaxf(v, __shfl_xor(v, 1));  v = fmaxf(v, __shfl_xor(v, 2));
  v = fmaxf(v, __shfl_xor(v, 4));  v = fmaxf(v, __shfl_xor(v, 8));
  v = fmaxf(v, __shfl_xor(v, 16)); v = fmaxf(v, __shfl_xor(v, 32));
  return v;
}
__device__ __forceinline__ float sigmoidf_(float x) { return 1.f / (1.f + __expf(-x)); }
__device__ __forceinline__ unsigned short f2b(float f) {
  unsigned u = __float_as_uint(f);
  return (unsigned short)((u + 0x7FFFu + ((u >> 16) & 1u)) >> 16);
}
__device__ __forceinline__ float b2f(unsigned short h) {
  return __uint_as_float(((unsigned)h) << 16);
}
__device__ __forceinline__ float dot4(float4 a, float4 b) {
  return a.x*b.x + a.y*b.y + a.z*b.z + a.w*b.w;
}

// ---------------- W2 = (ddqW[p]+I)*sc_d[p]  ->  bf16 split B2q (640 x 192, [hi|hi|lo]) ----------------
__global__ void build_w2b(const float* __restrict__ ddqW, const float* __restrict__ ddqT,
                          unsigned short* __restrict__ B2q) {
  int i = blockIdx.x * 256 + threadIdx.x;   // over 640*64
  if (i >= 640 * 64) return;
  int row = i >> 6, e = i & 63;
  int p = row >> 6, o = row & 63;
  float t = ddqT[p];
  float sp = log1pf(__expf(t));
  float scd = 1.f / ((sp + 1e-6f) * 8.0f);
  float w = (ddqW[(size_t)(p * 64 + o) * 64 + e] + (o == e ? 1.f : 0.f)) * scd;
  unsigned short h = f2b(w);
  unsigned short l = f2b(w - b2f(h));
  size_t base = (size_t)row * 192;
  B2q[base + e] = h; B2q[base + 64 + e] = h; B2q[base + 128 + e] = l;
}

// ---------------- bf16 split kernels ----------------
// PAT 0 (A-side): [hi | lo | hi]   PAT 1 (B-side): [hi | hi | lo]
template<int KSHIFT, int PAT>
__global__ void splitA(const float* __restrict__ in, unsigned short* __restrict__ out, int MK) {
  int i = (blockIdx.x * 256 + threadIdx.x) * 4;
  if (i >= MK) return;
  constexpr int K = 1 << KSHIFT;
  int m = i >> KSHIFT, k = i & (K - 1);
  float4 f = *(const float4*)(in + i);
  float fv[4] = {f.x, f.y, f.z, f.w};
  unsigned short h[4], l[4];
#pragma unroll
  for (int j = 0; j < 4; ++j) { h[j] = f2b(fv[j]); l[j] = f2b(fv[j] - b2f(h[j])); }
  size_t base = (size_t)m * (3 * K);
  ushort4 hv = {h[0], h[1], h[2], h[3]};
  ushort4 lv = {l[0], l[1], l[2], l[3]};
  if (PAT == 0) {
    *(ushort4*)(out + base + k) = hv;
    *(ushort4*)(out + base + K + k) = lv;
    *(ushort4*)(out + base + 2 * K + k) = hv;
  } else {
    *(ushort4*)(out + base + k) = hv;
    *(ushort4*)(out + base + K + k) = hv;
    *(ushort4*)(out + base + 2 * K + k) = lv;
  }
}

__global__ void splitB5(const float* __restrict__ w0, const float* __restrict__ w1,
                        const float* __restrict__ w2, const float* __restrict__ w3,
                        const float* __restrict__ w4, unsigned short* __restrict__ out) {
  int i = (blockIdx.x * 256 + threadIdx.x) * 4;   // over 2560*512
  if (i >= 2560 * 512) return;
  int nrow = i >> 9, k = i & 511;
  int sel = nrow >> 9;
  const float* w = sel == 0 ? w0 : sel == 1 ? w1 : sel == 2 ? w2 : sel == 3 ? w3 : w4;
  float4 f = *(const float4*)(w + (size_t)(nrow & 511) * 512 + k);
  float fv[4] = {f.x, f.y, f.z, f.w};
  unsigned short h[4], l[4];
#pragma unroll
  for (int j = 0; j < 4; ++j) { h[j] = f2b(fv[j]); l[j] = f2b(fv[j] - b2f(h[j])); }
  size_t base = (size_t)nrow * 1536;
  ushort4 hv = {h[0], h[1], h[2], h[3]};
  ushort4 lv = {l[0], l[1], l[2], l[3]};
  *(ushort4*)(out + base + k) = hv;
  *(ushort4*)(out + base + 512 + k) = hv;
  *(ushort4*)(out + base + 1024 + k) = lv;
}

// ---------------- MFMA GEMM: C[m][n] = sum_k A2[m][k] * B2[n][k] (both row-major [dim][K3] bf16) ----
// MODE 0: fused 5-way projection epilogue; MODE 1: Qall -> Qs; MODE 2: out-proj + bias
template<int MODE>
__global__ __launch_bounds__(256)
void gemm_mfma(const unsigned short* __restrict__ A2, const unsigned short* __restrict__ B2,
               int K3,
               const float* __restrict__ bq, const float* __restrict__ bv,
               const float* __restrict__ bkl, const float* __restrict__ bvl,
               const float* __restrict__ bgt,
               float* __restrict__ qbuf, float* __restrict__ bank,
               float* __restrict__ klbuf, float* __restrict__ vlbuf,
               float* __restrict__ gatebuf, float* __restrict__ Qs,
               float* __restrict__ oout, const float* __restrict__ ob)
{
  __shared__ __align__(16) unsigned short Asb[128 * 40];  // row stride 40 shorts = 80 B
  __shared__ __align__(16) unsigned short Bsb[128 * 40];
  const int tid = threadIdx.x;
  const int wave = tid >> 6, lane = tid & 63;
  const int wr = wave >> 1, wc = wave & 1;
  const int row0 = blockIdx.y * 128, col0 = blockIdx.x * 128;

  f32x4 acc[4][4];
#pragma unroll
  for (int i = 0; i < 4; ++i)
#pragma unroll
    for (int j = 0; j < 4; ++j) acc[i][j] = (f32x4){0.f, 0.f, 0.f, 0.f};

  const int srow = tid >> 1;
  const int shalf = tid & 1;
  const unsigned short* agp = A2 + (size_t)(row0 + srow) * K3 + shalf * 16;
  const unsigned short* bgp = B2 + (size_t)(col0 + srow) * K3 + shalf * 16;
  const int lrow = lane & 15, kslot = lane >> 4;

  for (int kt = 0; kt < K3; kt += 32) {
    int4 a0 = *(const int4*)(agp + kt);
    int4 a1 = *(const int4*)(agp + kt + 8);
    int4 b0 = *(const int4*)(bgp + kt);
    int4 b1 = *(const int4*)(bgp + kt + 8);
    __syncthreads();
    *(int4*)(Asb + srow * 40 + shalf * 16) = a0;
    *(int4*)(Asb + srow * 40 + shalf * 16 + 8) = a1;
    *(int4*)(Bsb + srow * 40 + shalf * 16) = b0;
    *(int4*)(Bsb + srow * 40 + shalf * 16 + 8) = b1;
    __syncthreads();
    bf16x8 af[4], bf[4];
#pragma unroll
    for (int m = 0; m < 4; ++m)
      af[m] = *(const bf16x8*)(Asb + (wr * 64 + m * 16 + lrow) * 40 + kslot * 8);
#pragma unroll
    for (int n = 0; n < 4; ++n)
      bf[n] = *(const bf16x8*)(Bsb + (wc * 64 + n * 16 + lrow) * 40 + kslot * 8);
#pragma unroll
    for (int m = 0; m < 4; ++m)
#pragma unroll
      for (int n = 0; n < 4; ++n)
        acc[m][n] = __builtin_amdgcn_mfma_f32_16x16x32_bf16(af[m], bf[n], acc[m][n], 0, 0, 0);
  }

#pragma unroll
  for (int m = 0; m < 4; ++m)
#pragma unroll
    for (int n = 0; n < 4; ++n)
#pragma unroll
      for (int r = 0; r < 4; ++r) {
        const int row = row0 + wr * 64 + m * 16 + (lane >> 4) * 4 + r;
        const int col = col0 + wc * 64 + n * 16 + (lane & 15);
        float v = acc[m][n][r];
        if (MODE == 0) {
          const int sel = col >> 9;
          const int c = col & 511;
          const int bb = row >> 10, nn = row & 1023;
          if (sel == 0) {
            qbuf[(size_t)row * 512 + c] = v + bq[c];
          } else if (sel == 1) {
            // v -> bank level 0, slot 0 (compact layout, KS[0]=1)
            bank[((size_t)(bb * 8 + (c >> 6)) * TOTV + nn) * 64 + (c & 63)] = v + bv[c];
          } else if (sel == 2) {
            klbuf[(size_t)row * 512 + c] = v + bkl[c];
          } else if (sel == 3) {
            vlbuf[(size_t)row * 512 + c] = v + bvl[c];
          } else {
            gatebuf[(size_t)row * 512 + c] = sigmoidf_(v + bgt[c]);
          }
        } else if (MODE == 1) {
          Qs[((size_t)(col >> 6) * 16384 + row) * 64 + (col & 63)] = v;
        } else {
          oout[(size_t)row * 512 + col] = v + ob[col];
        }
      }
}

// ---------------- tree level update v2 ----------------
template<int D, int NPB>
__global__ __launch_bounds__(512)
void level2(const float* __restrict__ glW, const float* __restrict__ glb,
            const float* __restrict__ grW, const float* __restrict__ grb,
            const float* __restrict__ pq, const float* __restrict__ lnG,
            const float* __restrict__ lnB, const float* __restrict__ skA,
            const float* __restrict__ skW, const float* __restrict__ coup,
            const float* __restrict__ wfreq, const float* __restrict__ wdamp,
            const float* __restrict__ wphase, float* __restrict__ bank)
{
  constexpr int KPREV = ((D - 1) >= 3) ? 8 : (1 << (D - 1));
  constexpr int SLOTS = 2 * KPREV;
  constexpr int KP = (D >= 3) ? 8 : (1 << D);
  constexpr int NODES = 1024 >> D;
  constexpr int VB_PREV = vbase_of(D - 1);
  constexpr int VB_CUR  = vbase_of(D);

  __shared__ __align__(16) float wl[32 * 256];    // [eg][o][4] of glW[D]
  __shared__ __align__(16) float wrr[32 * 256];   // grW[D]
  __shared__ __align__(16) float wsk[16 * 256];   // skW[D]
  __shared__ __align__(16) float gin[8][128];
  __shared__ float parlds[8][KP][64];

  const int tid = threadIdx.x;
  const int h = tid >> 6, lane = tid & 63;

  // stage all three weight matrices once, transposed-interleaved
  for (int i = tid; i < 64 * 128; i += 512) {
    int o = i >> 7, e = i & 127;
    float v = glW[(size_t)D * 8192 + i];
    wl[(e >> 2) * 256 + o * 4 + (e & 3)] = v;
    float v2 = grW[(size_t)D * 8192 + i];
    wrr[(e >> 2) * 256 + o * 4 + (e & 3)] = v2;
  }
  for (int i = tid; i < 64 * 64; i += 512) {
    int o = i >> 6, e = i & 63;
    wsk[(e >> 2) * 256 + o * 4 + (e & 3)] = skW[(size_t)D * 4096 + i];
  }
  __syncthreads();

  const float alpha = log1pf(__expf(wdamp[h]));
  const float dec = __expf(-alpha);
  const float ang = wfreq[h] + wphase[h] + (float)D * 0.78539816339744831f;
  const float pr  = dec * cosf(ang);
  const float pim = dec * sinf(ang);
  const float glbv = glb[D * 64 + lane], grbv = grb[D * 64 + lane];
  const float lnGv = lnG[D * 64 + lane], lnBv = lnB[D * 64 + lane];
  const float sig_sk = sigmoidf_(skA[D]);
  float pqv[KP];
#pragma unroll
  for (int qi = 0; qi < KP; ++qi) pqv[qi] = pq[(size_t)(D * 8 + qi) * 64 + lane];
  float cw[8];
  float cmx = -1e30f;
#pragma unroll
  for (int j = 0; j < 8; ++j) { cw[j] = coup[(size_t)(D * 8 + h) * 8 + j]; cmx = fmaxf(cmx, cw[j]); }
  float cs = 0.f;
#pragma unroll
  for (int j = 0; j < 8; ++j) { cw[j] = __expf(cw[j] - cmx); cs += cw[j]; }
  const float cinv = 1.f / cs;

  const size_t bh = (size_t)blockIdx.y * 8 + h;
  const float* prevb = bank + (bh * TOTV + VB_PREV) * 64;
  float* curb = bank + (bh * TOTV + VB_CUR) * 64;

  for (int nn = 0; nn < NPB; ++nn) {
    const int node = blockIdx.x * NPB + nn;
    if (node < NODES) {
      float fL[KPREV], rot[KPREV];
      float lm = 0.f, rm = 0.f;
#pragma unroll
      for (int k = 0; k < KPREV; ++k) {
        fL[k] = prevb[(size_t)((2 * node) * KPREV + k) * 64 + lane];
        float fr = prevb[(size_t)((2 * node + 1) * KPREV + k) * 64 + lane];
        float partner = __shfl_xor(fr, 32);
        rot[k] = (lane < 32) ? (pr * fr - pim * partner) : (pim * partner + pr * fr);
        lm += fL[k]; rm += rot[k];
      }
      lm *= (1.f / KPREV); rm *= (1.f / KPREV);
      gin[h][lane] = lm;
      gin[h][64 + lane] = rm;     // same-wave write->read: no barrier needed

      float gl = glbv, gr = grbv, sk = 0.f;
#pragma unroll
      for (int eg = 0; eg < 32; ++eg) {
        float4 g4 = *(const float4*)&gin[h][eg * 4];
        float4 wv = *(const float4*)&wl[eg * 256 + lane * 4];
        float4 wv2 = *(const float4*)&wrr[eg * 256 + lane * 4];
        gl += dot4(g4, wv);
        gr += dot4(g4, wv2);
        if (eg < 16) {
          float4 w3 = *(const float4*)&wsk[eg * 256 + lane * 4];
          sk += dot4(g4, w3);
        }
      }
      gl = sigmoidf_(gl); gr = sigmoidf_(gr);

      float slot[SLOTS];
#pragma unroll
      for (int k = 0; k < KPREV; ++k) { slot[k] = fL[k] * gl; slot[KPREV + k] = rot[k] * gr; }

      float par[KP];
#pragma unroll
      for (int qi = 0; qi < KP; ++qi) {
        float lg[SLOTS];
        float mx = -1e30f;
#pragma unroll
        for (int kk = 0; kk < SLOTS; ++kk) {
          lg[kk] = wsum(pqv[qi] * slot[kk]) * 0.125f;
          mx = fmaxf(mx, lg[kk]);
        }
        float den = 0.f, pv = 0.f;
#pragma unroll
        for (int kk = 0; kk < SLOTS; ++kk) {
          float w = __expf(lg[kk] - mx);
          den += w; pv += w * slot[kk];
        }
        par[qi] = pv / den;
      }

#pragma unroll
      for (int qi = 0; qi < KP; ++qi) {
        float mu = wsum(par[qi]) * (1.f / 64.f);
        float dv = par[qi] - mu;
        float var = wsum(dv * dv) * (1.f / 64.f);
        float nv = dv * rsqrtf(var + 1e-5f);
        par[qi] = nv * lnGv + lnBv + sig_sk * sk;
        parlds[h][qi][lane] = par[qi];
      }
    }
    __syncthreads();
    if (node < NODES) {
#pragma unroll
      for (int qi = 0; qi < KP; ++qi) {
        float o = 0.f;
#pragma unroll
        for (int j = 0; j < 8; ++j) o += cw[j] * parlds[j][qi][lane];
        curb[(size_t)(node * KP + qi) * 64 + lane] = o * cinv;
      }
    }
    __syncthreads();
  }
}

// ---------------- local window attn + tree attn + gate combine ----------------
__global__ __launch_bounds__(512)
void combine_kernel(const float* __restrict__ qbuf, const float* __restrict__ klbuf,
                    const float* __restrict__ vlbuf, const float* __restrict__ gatebuf,
                    const float* __restrict__ bank, const float* __restrict__ Qs,
                    float* __restrict__ outpre)
{
  const int n = blockIdx.x;
  const int b = blockIdx.y;
  const int h = threadIdx.x >> 6;
  const int lane = threadIdx.x & 63;
  __shared__ int pair_ro[64];
  __shared__ int pair_sl[64];
  __shared__ int sdepth[16];
  __shared__ int PS[2];
  __shared__ __align__(16) float Qlds[8][10][68];

  if (threadIdx.x == 0) {
    int l = 2048, r = 2048 + n;
    int cnt = 0, sc = 0;
    while (l < r) {
      if (l & 1) {
        int m = l++;
        int j = 31 - __clz(m);
        int d = 11 - j;
        int local = m - (1 << j);
        int kv = (d >= 3) ? 8 : (1 << d);
        sdepth[sc] = d;
        int vb = VBASE[d] + local * kv;
        for (int k = 0; k < kv; ++k) { pair_ro[cnt] = (vb + k) * 64; pair_sl[cnt] = sc; ++cnt; }
        ++sc;
      }
      if (r & 1) {
        int m = --r;
        int j = 31 - __clz(m);
        int d = 11 - j;
        int local = m - (1 << j);
        int kv = (d >= 3) ? 8 : (1 << d);
        sdepth[sc] = d;
        int vb = VBASE[d] + local * kv;
        for (int k = 0; k < kv; ++k) { pair_ro[cnt] = (vb + k) * 64; pair_sl[cnt] = sc; ++cnt; }
        ++sc;
      }
      l >>= 1; r >>= 1;
    }
    PS[0] = cnt; PS[1] = sc;
  }
  __syncthreads();
  const int P = PS[0], S = PS[1];
  const size_t vbase = ((size_t)(b * N_ + n) * H_ + h) * 64;

  for (int s = 0; s < S; ++s) {
    int d = sdepth[s];
    Qlds[h][s][lane] = Qs[((size_t)d * 16384 + (size_t)(b * N_ + n) * H_ + h) * 64 + lane];
  }
  __syncthreads();

  // ---- local sliding-window attention ----
  float qv = qbuf[vbase + lane];
  const int wmax = (n + 1 < 32) ? (n + 1) : 32;
  float myscore = -1e30f;
  for (int w = 0; w < wmax; ++w) {
    float kv = klbuf[vbase - (size_t)w * 512 + lane];
    float s = wsum(qv * kv) * 0.125f;
    if (lane == w) myscore = s;
  }
  float lmax = wmaxr(myscore);
  float le = (lane < wmax) ? __expf(myscore - lmax) : 0.f;
  float lden = wsum(le);
  float lp = le / lden;
  float local = 0.f;
  for (int w = 0; w < wmax; ++w) {
    float pw = __shfl(lp, w);
    local += pw * vlbuf[vbase - (size_t)w * 512 + lane];
  }

  // ---- tree attention ----
  const size_t bhbase = (size_t)(b * H_ + h) * TOTV * 64;
  float tree = 0.f;
  if (P > 0) {
    float logit = -1e30f;
    if (lane < P) {
      const float4* b4 = (const float4*)(bank + bhbase + pair_ro[lane]);
      const float4* q4 = (const float4*)&Qlds[h][pair_sl[lane]][0];
      float a = 0.f;
#pragma unroll
      for (int i = 0; i < 16; ++i) {
        float4 bb = b4[i];
        float4 qq = q4[i];
        a += qq.x * bb.x + qq.y * bb.y + qq.z * bb.z + qq.w * bb.w;
      }
      logit = a;
    }
    float tm = wmaxr(logit);
    float te = (lane < P) ? __expf(logit - tm) : 0.f;
    float tden = wsum(te);
    float tw = te / tden;
    for (int l2 = 0; l2 < P; ++l2) {
      float wl_ = __shfl(tw, l2);
      tree += wl_ * bank[bhbase + pair_ro[l2] + lane];
    }
  }

  float g = gatebuf[vbase + lane];
  outpre[vbase + lane] = local + g * tree;
}

// ---------------- launcher ----------------
extern "C" void kernel_launch(void* const* d_in, const int* in_sizes, int n_in,
                              void* d_out, int out_size, void* d_ws, size_t ws_size,
                              hipStream_t stream)
{
  (void)in_sizes; (void)n_in; (void)out_size; (void)ws_size;
  const float* x     = (const float*)d_in[0];
  const float* qW    = (const float*)d_in[1];
  const float* qb    = (const float*)d_in[2];
  const float* vW    = (const float*)d_in[3];
  const float* vb    = (const float*)d_in[4];
  const float* oW    = (const float*)d_in[5];
  const float* ob    = (const float*)d_in[6];
  const float* klW   = (const float*)d_in[7];
  const float* klb   = (const float*)d_in[8];
  const float* vlW   = (const float*)d_in[9];
  const float* vlb   = (const float*)d_in[10];
  const float* gW    = (const float*)d_in[11];
  const float* gb    = (const float*)d_in[12];
  const float* ddqW  = (const float*)d_in[13];
  const float* ddqT  = (const float*)d_in[14];
  const float* wfreq = (const float*)d_in[15];
  const float* wdamp = (const float*)d_in[16];
  const float* wphase= (const float*)d_in[17];
  const float* glW   = (const float*)d_in[18];
  const float* glb   = (const float*)d_in[19];
  const float* grW   = (const float*)d_in[20];
  const float* grb   = (const float*)d_in[21];
  const float* pq    = (const float*)d_in[22];
  const float* lnG   = (const float*)d_in[23];
  const float* lnB   = (const float*)d_in[24];
  const float* skA   = (const float*)d_in[25];
  const float* skW   = (const float*)d_in[26];
  const float* coup  = (const float*)d_in[27];

  float* ws = (float*)d_ws;
  float* qbuf    = ws; ws += (size_t)2048 * 512;
  float* klbuf   = ws; ws += (size_t)2048 * 512;
  float* vlbuf   = ws; ws += (size_t)2048 * 512;
  float* gatebuf = ws; ws += (size_t)2048 * 512;
  float* outpre  = ws; ws += (size_t)2048 * 512;
  float* bank    = ws; ws += (size_t)16 * TOTV * 64;   // 20.9 MB compact
  float* Qs      = ws; ws += (size_t)10 * 16384 * 64;
  unsigned short* A2x = (unsigned short*)ws; ws += (size_t)2048 * 1536 / 2;
  unsigned short* B2w = (unsigned short*)ws; ws += (size_t)2560 * 1536 / 2;
  unsigned short* A2q = (unsigned short*)ws; ws += (size_t)16384 * 192 / 2;
  unsigned short* B2q = (unsigned short*)ws; ws += (size_t)640 * 192 / 2;
  unsigned short* A2o = (unsigned short*)ws; ws += (size_t)2048 * 1536 / 2;
  unsigned short* B2o = (unsigned short*)ws; ws += (size_t)512 * 1536 / 2;

  build_w2b<<<160, 256, 0, stream>>>(ddqW, ddqT, B2q);
  splitA<9, 0><<<1024, 256, 0, stream>>>(x, A2x, 2048 * 512);
  splitB5<<<1280, 256, 0, stream>>>(qW, vW, klW, vlW, gW, B2w);

  // fused projections: q | v->bank L0 | k_loc | v_loc | sigmoid-gate
  gemm_mfma<0><<<dim3(20, 16), 256, 0, stream>>>(A2x, B2w, 1536,
      qb, vb, klb, vlb, gb, qbuf, bank, klbuf, vlbuf, gatebuf, nullptr, nullptr, nullptr);

  // depth-queries
  splitA<6, 0><<<1024, 256, 0, stream>>>(qbuf, A2q, 16384 * 64);
  gemm_mfma<1><<<dim3(5, 128), 256, 0, stream>>>(A2q, B2q, 192,
      nullptr, nullptr, nullptr, nullptr, nullptr,
      nullptr, nullptr, nullptr, nullptr, nullptr, Qs, nullptr, nullptr);

#define LVL(DD, NPB) level2<DD, NPB><<<dim3((1024 >> DD) / NPB, 2), 512, 0, stream>>>( \
      glW, glb, grW, grb, pq, lnG, lnB, skA, skW, coup, wfreq, wdamp, wphase, bank)
  LVL(1, 4); LVL(2, 2); LVL(3, 1); LVL(4, 1); LVL(5, 1);
  LVL(6, 1); LVL(7, 1); LVL(8, 1); LVL(9, 1);
#undef LVL

  combine_kernel<<<dim3(1024, 2), 512, 0, stream>>>(qbuf, klbuf, vlbuf, gatebuf, bank, Qs, outpre);

  // final projection
  splitA<9, 0><<<1024, 256, 0, stream>>>(outpre, A2o, 2048 * 512);
  splitA<9, 1><<<256, 256, 0, stream>>>(oW, B2o, 512 * 512);
  gemm_mfma<2><<<dim3(4, 16), 256, 0, stream>>>(A2o, B2o, 1536,
      nullptr, nullptr, nullptr, nullptr, nullptr,
      nullptr, nullptr, nullptr, nullptr, nullptr, nullptr, (float*)d_out, ob);
}